// Round 3
// baseline (387.624 us; speedup 1.0000x reference)
//
#include <hip/hip_runtime.h>

// SDPAttention (bug-faithful: output = masked_scores @ v, NOT softmax @ v)
// B=4 H=16 S=1024 DK=64, fp32 in/out.
// R6 post-mortem: nt-stores suspected regression (~+17us); K-halving gave
// no visible win -> issued-traffic reduction must be bigger to show.
// R7 (this round): Qtile 64, 1024-thr blocks, 16 waves, FULL intra-block
// K/V dedup:
//   - phase1: wave w owns kt [w*4,w*4+4), computes ALL 4 row-groups per
//     K-fragment load -> K issued 128 KB/block (256 MB -> 128 MB total).
//   - phase3: only 4 PV waves (one per d-tile cg); each V fragment loaded
//     ONCE feeds 4 rg MFMAs -> V issued 128 KB/block (512 -> 128 MB).
//   - 12 SM waves do the 64-row softmax + attn_weight write concurrently
//     (write-stream pipe) while PV waves run MFMA/LDS/V-read pipes.
// nt-stores reverted; XCD-bijective swizzle kept; SCN 1040->1048 (row
// stride 524 dwords == 12 mod 32: phase-3 ds_read_b128 4-way -> 2-way).
// d_ws: [0,8MB) KbT[bh][kt][lane][16]; [8MB,16MB) VtP[bh][dt][ks][lane][8]

typedef __attribute__((ext_vector_type(4))) float floatx4;
typedef __attribute__((ext_vector_type(8))) short shortx8;
typedef __attribute__((ext_vector_type(8))) unsigned short ushortx8;

#define S_ 1024
#define D_ 64
#define NELEM_ 4194304      // B*H*S*DK
#define ATTN_OFF 4194304    // output elements before attn_weight
#define SCN 1048            // LDS score row stride (ushorts); 2096B rows
#define QT 64               // q rows per block

__device__ __forceinline__ unsigned short f32_to_bf16(float f) {
    union { float f; unsigned u; } a; a.f = f;
    unsigned u = a.u;
    u += 0x7fffu + ((u >> 16) & 1u);   // round-to-nearest-even
    return (unsigned short)(u >> 16);
}

__device__ __forceinline__ float bf16_to_f32(unsigned short h) {
    union { unsigned u; float f; } a; a.u = ((unsigned)h) << 16;
    return a.f;
}

__device__ __forceinline__ ushortx8 pack8u(floatx4 a, floatx4 b) {
    ushortx8 r;
    r[0] = f32_to_bf16(a[0]); r[1] = f32_to_bf16(a[1]);
    r[2] = f32_to_bf16(a[2]); r[3] = f32_to_bf16(a[3]);
    r[4] = f32_to_bf16(b[0]); r[5] = f32_to_bf16(b[1]);
    r[6] = f32_to_bf16(b[2]); r[7] = f32_to_bf16(b[3]);
    return r;
}

// ---- merged pre-kernel: blocks [0,1024) pack K, [1024,2048) pack V ----
__global__ __launch_bounds__(256) void pack_kv(const float* __restrict__ k,
                                               const float* __restrict__ v,
                                               unsigned short* __restrict__ kbt,
                                               unsigned short* __restrict__ vtp) {
    __shared__ float tile[64][65];
    if (blockIdx.x < 1024) {
        // K fp32 [bh][s][d] -> KbT fragment-major bf16
        int g = blockIdx.x * 256 + threadIdx.x;   // 262144 total
        int lane = g & 63;
        int kt   = (g >> 6) & 63;
        int bh   = g >> 12;
        int quad = lane >> 4;
        int l15  = lane & 15;
        const float* src = k + ((size_t)(bh * S_ + kt * 16 + l15)) * D_ + quad * 8;
        floatx4 f0 = *(const floatx4*)(src);
        floatx4 f1 = *(const floatx4*)(src + 4);
        floatx4 f2 = *(const floatx4*)(src + 32);
        floatx4 f3 = *(const floatx4*)(src + 36);
        unsigned short* dst = kbt + (size_t)g * 16;
        *(ushortx8*)(dst)     = pack8u(f0, f1);
        *(ushortx8*)(dst + 8) = pack8u(f2, f3);
    } else {
        // V fp32 [bh][s][d] -> VtP fragment-major bf16 via LDS transpose
        int blk = blockIdx.x - 1024;
        int bh = blk >> 4;
        int s0 = (blk & 15) << 6;
        int tid = threadIdx.x;
        int r  = tid >> 2;
        int c0 = (tid & 3) << 4;
        const float* src = v + ((size_t)(bh * S_ + s0 + r)) * D_ + c0;
        #pragma unroll
        for (int j = 0; j < 4; ++j) {
            floatx4 f = *(const floatx4*)(src + j * 4);
            tile[r][c0 + j*4 + 0] = f[0];
            tile[r][c0 + j*4 + 1] = f[1];
            tile[r][c0 + j*4 + 2] = f[2];
            tile[r][c0 + j*4 + 3] = f[3];
        }
        __syncthreads();
        int d  = tid >> 2;          // 0..63
        int so = (tid & 3) << 4;    // 0,16,32,48
        int dt  = d >> 4;
        int l15 = d & 15;
        ushortx8 h0, h1;
        #pragma unroll
        for (int j = 0; j < 8; ++j) h0[j] = f32_to_bf16(tile[so + j][d]);
        #pragma unroll
        for (int j = 0; j < 8; ++j) h1[j] = f32_to_bf16(tile[so + 8 + j][d]);
        int sA = s0 + so;
        int ksA = sA >> 5, qA = (sA & 31) >> 3;
        int sB = sA + 8;
        int ksB = sB >> 5, qB = (sB & 31) >> 3;
        size_t baseA = ((((size_t)bh * 4 + dt) * 32 + ksA) * 64 + qA * 16 + l15) * 8;
        size_t baseB = ((((size_t)bh * 4 + dt) * 32 + ksB) * 64 + qB * 16 + l15) * 8;
        *(ushortx8*)(vtp + baseA) = h0;
        *(ushortx8*)(vtp + baseB) = h1;
    }
}

// ---- main: per-block = (bh, 64-row q tile); 16 waves ----
// Phase 1: wave w owns kt-slice [w*4, w*4+4), computes ALL 4 row-groups.
// Phase 2: waves 0..11 do softmax rows (6,6,6,6,5,5,5,5,5,5,5,5).
// Phase 3: waves 12..15 = PV wave for cg = w-12; each V frag read once,
//          feeds 4 rg MFMAs.
__global__ __launch_bounds__(1024, 4) void attn_main(
    const float* __restrict__ q,
    const int* __restrict__ mask,
    const unsigned short* __restrict__ KbT,
    const unsigned short* __restrict__ VtP,
    float* __restrict__ out)
{
    __shared__ unsigned short sc[QT * SCN];   // 134,144 B masked scaled scores (bf16)
    __shared__ int msk[1024];

    // XCD-bijective swizzle: 1024 blocks, 128 consecutive logical blocks
    // per XCD -> per-XCD concurrent K/V working set ~512 KB (fits L2).
    int blk = ((blockIdx.x & 7) << 7) | (blockIdx.x >> 3);
    int bh  = blk >> 4;
    int q0  = (blk & 15) << 6;
    int b   = bh >> 4;
    int tid = threadIdx.x;

    msk[tid] = mask[(b << 10) + tid];

    int w    = tid >> 6;              // 0..15
    int lane = tid & 63;
    int l15  = lane & 15;
    int quad = lane >> 4;

    // Q fragments for ALL 4 row-groups (A: m=lane&15, k=quad*8+j)
    shortx8 qf0[4], qf1[4];
    #pragma unroll
    for (int rg = 0; rg < 4; ++rg) {
        const float* qb = q + ((size_t)(bh * S_ + q0 + rg * 16 + l15)) * D_ + quad * 8;
        floatx4 a0 = *(const floatx4*)(qb);
        floatx4 a1 = *(const floatx4*)(qb + 4);
        floatx4 a2 = *(const floatx4*)(qb + 32);
        floatx4 a3 = *(const floatx4*)(qb + 36);
        qf0[rg] = (shortx8)pack8u(a0, a1);
        qf1[rg] = (shortx8)pack8u(a2, a3);
    }

    __syncthreads();

    // ---- Phase 1: Sc = scale*QK^T, masked, -> LDS bf16 ----
    // Each K fragment loaded ONCE per block, feeds 8 MFMAs (4 rg x 2 k-halves).
    {
        const unsigned short* kb = KbT + ((size_t)bh * 64 * 64 + lane) * 16;
        #pragma unroll
        for (int t = 0; t < 4; ++t) {
            int kt = (w << 2) + t;
            const unsigned short* p = kb + (size_t)kt * (64 * 16);
            shortx8 kf0 = *(const shortx8*)(p);       // coalesced: lane*32B
            shortx8 kf1 = *(const shortx8*)(p + 8);
            floatx4 acc[4];
            #pragma unroll
            for (int rg = 0; rg < 4; ++rg) {
                acc[rg] = (floatx4){0.f, 0.f, 0.f, 0.f};
                acc[rg] = __builtin_amdgcn_mfma_f32_16x16x32_bf16(qf0[rg], kf0, acc[rg], 0, 0, 0);
                acc[rg] = __builtin_amdgcn_mfma_f32_16x16x32_bf16(qf1[rg], kf1, acc[rg], 0, 0, 0);
            }
            int n0 = kt << 4;
            int mv = msk[n0 + l15];
            int col = n0 + l15;
            #pragma unroll
            for (int rg = 0; rg < 4; ++rg) {
                #pragma unroll
                for (int r = 0; r < 4; ++r) {
                    // C/D: row(q within 16-tile) = quad*4+r, col(key) = lane&15
                    unsigned short h = mv ? f32_to_bf16(acc[rg][r] * 0.125f)
                                          : (unsigned short)0xC61C;  // bf16(-10000)
                    sc[(rg * 16 + quad * 4 + r) * SCN + col] = h;
                }
            }
        }
    }
    __syncthreads();

    // ---- Phase 2 (waves 0..11): row softmax -> attn_weight ----
    // ---- Phase 3 (waves 12..15): O = Sc @ V, V dedup'd             ----
    // Independent (reference bug: O uses raw masked scores).
    if (w < 12) {
        int nrows = (w < 4) ? 6 : 5;
        int row0  = (w < 4) ? w * 6 : 24 + (w - 4) * 5;
        float* attnb = out + ATTN_OFF + ((size_t)(bh * S_ + q0)) * S_;
        for (int rr = 0; rr < nrows; ++rr) {
            int row = row0 + rr;
            const unsigned short* srow = sc + row * SCN;
            float vv[16];
            #pragma unroll
            for (int c = 0; c < 2; ++c) {
                ushortx8 h = *(const ushortx8*)(srow + (c << 9) + lane * 8);
                #pragma unroll
                for (int j = 0; j < 8; ++j) vv[c * 8 + j] = bf16_to_f32(h[j]);
            }
            float m = vv[0];
            #pragma unroll
            for (int j = 1; j < 16; ++j) m = fmaxf(m, vv[j]);
            #pragma unroll
            for (int off = 32; off; off >>= 1) m = fmaxf(m, __shfl_xor(m, off));
            float s = 0.f;
            #pragma unroll
            for (int j = 0; j < 16; ++j) { vv[j] = __expf(vv[j] - m); s += vv[j]; }
            #pragma unroll
            for (int off = 32; off; off >>= 1) s += __shfl_xor(s, off);
            float inv = 1.0f / s;
            float* arow = attnb + (size_t)row * S_ + lane * 8;
            #pragma unroll
            for (int c = 0; c < 2; ++c) {
                floatx4 o0 = { vv[c*8+0]*inv, vv[c*8+1]*inv, vv[c*8+2]*inv, vv[c*8+3]*inv };
                floatx4 o1 = { vv[c*8+4]*inv, vv[c*8+5]*inv, vv[c*8+6]*inv, vv[c*8+7]*inv };
                *(floatx4*)(arow + (c << 9))     = o0;
                *(floatx4*)(arow + (c << 9) + 4) = o1;
            }
        }
    } else {
        // PV wave: cg = w-12 owns d cols [cg*16, cg*16+16) for ALL 64 rows.
        int cg = w - 12;
        const unsigned short* vb = VtP + (((size_t)bh * 4 + cg) * 32) * (64 * 8) + lane * 8;
        const unsigned short* srb = sc + l15 * SCN + quad * 8;
        floatx4 oacc[4];
        #pragma unroll
        for (int rg = 0; rg < 4; ++rg) oacc[rg] = (floatx4){0.f, 0.f, 0.f, 0.f};
        #pragma unroll 4
        for (int ks = 0; ks < 32; ++ks) {
            shortx8 bfr = *(const shortx8*)(vb + (ks << 9));       // V frag: once
            #pragma unroll
            for (int rg = 0; rg < 4; ++rg) {
                shortx8 af = *(const shortx8*)(srb + (rg * 16) * SCN + (ks << 5));
                oacc[rg] = __builtin_amdgcn_mfma_f32_16x16x32_bf16(af, bfr, oacc[rg], 0, 0, 0);
            }
        }
        #pragma unroll
        for (int rg = 0; rg < 4; ++rg) {
            float* ob = out + ((size_t)(bh * S_ + q0 + rg * 16 + (quad << 2))) * D_
                            + (cg << 4) + l15;
            #pragma unroll
            for (int r = 0; r < 4; ++r) ob[(size_t)r * D_] = oacc[rg][r];
        }
    }
}

extern "C" void kernel_launch(void* const* d_in, const int* in_sizes, int n_in,
                              void* d_out, int out_size, void* d_ws, size_t ws_size,
                              hipStream_t stream) {
    const float* q   = (const float*)d_in[0];
    const float* k   = (const float*)d_in[1];
    const float* v   = (const float*)d_in[2];
    const int* mask  = (const int*)d_in[3];
    float* out = (float*)d_out;
    unsigned short* KbT = (unsigned short*)d_ws;       // 8 MB
    unsigned short* VtP = KbT + NELEM_;                // 8 MB
    pack_kv<<<2048, 256, 0, stream>>>(k, v, KbT, VtP);
    attn_main<<<1024, 1024, 0, stream>>>(q, mask, KbT, VtP, out);
}

// Round 4
// 376.278 us; speedup vs baseline: 1.0302x; 1.0302x over previous
//
#include <hip/hip_runtime.h>

// SDPAttention (bug-faithful: output = masked_scores @ v, NOT softmax @ v)
// B=4 H=16 S=1024 DK=64, fp32 in/out.
// R6/R7 post-mortem: issued-traffic reductions gave ZERO win (reads are
// L2/L3-served); every config so far ran at exactly 4 waves/SIMD (16
// waves/CU, LDS-capped) -> kernel is global-latency-bound with fixed
// latency hiding. R8: double residency to 8 waves/SIMD (HW max 32/CU):
//   - Qtile 16, 512-thr blocks (8 waves), score tile 33.5 KB LDS
//     -> 4 blocks/CU x 8 waves = 32 waves/CU.
//   - msk[] LDS copy dropped (mask read straight from global, L1-served)
//     -> LDS < 40 KB AND prologue barrier eliminated (1 barrier total).
//   - phase1: wave w owns kt [8w,8w+8), 1 row-group (reg-light).
//   - phase2/3 role split 4/4: SM waves 0-3 (4 rows each), PV waves 4-7
//     (one d-tile each, 32-MFMA chain, same as R5; NOT R7's 128).
//   - __launch_bounds__(512,8): cap 64 VGPR so LDS, not VGPR, limits.
//   - XCD-bijective swizzle kept (4096 blocks -> 8 bh/XCD, 2MB < L2).
// d_ws: [0,8MB) KbT[bh][kt][lane][16]; [8MB,16MB) VtP[bh][dt][ks][lane][8]

typedef __attribute__((ext_vector_type(4))) float floatx4;
typedef __attribute__((ext_vector_type(8))) short shortx8;
typedef __attribute__((ext_vector_type(8))) unsigned short ushortx8;

#define S_ 1024
#define D_ 64
#define NELEM_ 4194304      // B*H*S*DK
#define ATTN_OFF 4194304    // output elements before attn_weight
#define SCN 1048            // LDS score row stride (ushorts); 2096B rows
#define QT 16               // q rows per block

__device__ __forceinline__ unsigned short f32_to_bf16(float f) {
    union { float f; unsigned u; } a; a.f = f;
    unsigned u = a.u;
    u += 0x7fffu + ((u >> 16) & 1u);   // round-to-nearest-even
    return (unsigned short)(u >> 16);
}

__device__ __forceinline__ float bf16_to_f32(unsigned short h) {
    union { unsigned u; float f; } a; a.u = ((unsigned)h) << 16;
    return a.f;
}

__device__ __forceinline__ ushortx8 pack8u(floatx4 a, floatx4 b) {
    ushortx8 r;
    r[0] = f32_to_bf16(a[0]); r[1] = f32_to_bf16(a[1]);
    r[2] = f32_to_bf16(a[2]); r[3] = f32_to_bf16(a[3]);
    r[4] = f32_to_bf16(b[0]); r[5] = f32_to_bf16(b[1]);
    r[6] = f32_to_bf16(b[2]); r[7] = f32_to_bf16(b[3]);
    return r;
}

// ---- merged pre-kernel: blocks [0,1024) pack K, [1024,2048) pack V ----
__global__ __launch_bounds__(256) void pack_kv(const float* __restrict__ k,
                                               const float* __restrict__ v,
                                               unsigned short* __restrict__ kbt,
                                               unsigned short* __restrict__ vtp) {
    __shared__ float tile[64][65];
    if (blockIdx.x < 1024) {
        // K fp32 [bh][s][d] -> KbT fragment-major bf16
        int g = blockIdx.x * 256 + threadIdx.x;   // 262144 total
        int lane = g & 63;
        int kt   = (g >> 6) & 63;
        int bh   = g >> 12;
        int quad = lane >> 4;
        int l15  = lane & 15;
        const float* src = k + ((size_t)(bh * S_ + kt * 16 + l15)) * D_ + quad * 8;
        floatx4 f0 = *(const floatx4*)(src);
        floatx4 f1 = *(const floatx4*)(src + 4);
        floatx4 f2 = *(const floatx4*)(src + 32);
        floatx4 f3 = *(const floatx4*)(src + 36);
        unsigned short* dst = kbt + (size_t)g * 16;
        *(ushortx8*)(dst)     = pack8u(f0, f1);
        *(ushortx8*)(dst + 8) = pack8u(f2, f3);
    } else {
        // V fp32 [bh][s][d] -> VtP fragment-major bf16 via LDS transpose
        int blk = blockIdx.x - 1024;
        int bh = blk >> 4;
        int s0 = (blk & 15) << 6;
        int tid = threadIdx.x;
        int r  = tid >> 2;
        int c0 = (tid & 3) << 4;
        const float* src = v + ((size_t)(bh * S_ + s0 + r)) * D_ + c0;
        #pragma unroll
        for (int j = 0; j < 4; ++j) {
            floatx4 f = *(const floatx4*)(src + j * 4);
            tile[r][c0 + j*4 + 0] = f[0];
            tile[r][c0 + j*4 + 1] = f[1];
            tile[r][c0 + j*4 + 2] = f[2];
            tile[r][c0 + j*4 + 3] = f[3];
        }
        __syncthreads();
        int d  = tid >> 2;          // 0..63
        int so = (tid & 3) << 4;    // 0,16,32,48
        int dt  = d >> 4;
        int l15 = d & 15;
        ushortx8 h0, h1;
        #pragma unroll
        for (int j = 0; j < 8; ++j) h0[j] = f32_to_bf16(tile[so + j][d]);
        #pragma unroll
        for (int j = 0; j < 8; ++j) h1[j] = f32_to_bf16(tile[so + 8 + j][d]);
        int sA = s0 + so;
        int ksA = sA >> 5, qA = (sA & 31) >> 3;
        int sB = sA + 8;
        int ksB = sB >> 5, qB = (sB & 31) >> 3;
        size_t baseA = ((((size_t)bh * 4 + dt) * 32 + ksA) * 64 + qA * 16 + l15) * 8;
        size_t baseB = ((((size_t)bh * 4 + dt) * 32 + ksB) * 64 + qB * 16 + l15) * 8;
        *(ushortx8*)(vtp + baseA) = h0;
        *(ushortx8*)(vtp + baseB) = h1;
    }
}

// ---- main: per-block = (bh, 16-row q tile); 8 waves; 4 blocks/CU ----
// Phase 1: wave w owns kt-slice [w*8, w*8+8), single 16-row group.
// Phase 2 (waves 0..3): softmax rows [w*4, w*4+4) -> attn_weight.
// Phase 3 (waves 4..7): PV for d-tile cg = w-4 (32-MFMA chain).
__global__ __launch_bounds__(512, 8) void attn_main(
    const float* __restrict__ q,
    const int* __restrict__ mask,
    const unsigned short* __restrict__ KbT,
    const unsigned short* __restrict__ VtP,
    float* __restrict__ out)
{
    __shared__ unsigned short sc[QT * SCN];   // 33,536 B masked scaled scores (bf16)

    // XCD-bijective swizzle: 4096 blocks; 512 consecutive logical blocks
    // per XCD -> 8 bh per XCD -> K/V slice 2 MB < 4 MB private L2.
    int blk = ((blockIdx.x & 7) << 9) | (blockIdx.x >> 3);
    int bh  = blk >> 6;
    int q0  = (blk & 63) << 4;
    int b   = bh >> 4;
    int tid = threadIdx.x;

    int w    = tid >> 6;              // 0..7
    int lane = tid & 63;
    int l15  = lane & 15;
    int quad = lane >> 4;
    const int* mrow = mask + (b << 10);

    // Q fragments (A: m=lane&15 (q row within tile), k=quad*8+j (d))
    shortx8 qf0, qf1;
    {
        const float* qb = q + ((size_t)(bh * S_ + q0 + l15)) * D_ + quad * 8;
        floatx4 a0 = *(const floatx4*)(qb);
        floatx4 a1 = *(const floatx4*)(qb + 4);
        floatx4 a2 = *(const floatx4*)(qb + 32);
        floatx4 a3 = *(const floatx4*)(qb + 36);
        qf0 = (shortx8)pack8u(a0, a1);
        qf1 = (shortx8)pack8u(a2, a3);
    }

    // ---- Phase 1: Sc = scale*QK^T, masked, -> LDS bf16 ----
    // (no barrier needed before: each wave reads only its own qf)
    {
        const unsigned short* kb = KbT + ((size_t)bh * 64 * 64 + lane) * 16;
        #pragma unroll 2
        for (int t = 0; t < 8; ++t) {
            int kt = (w << 3) + t;
            const unsigned short* p = kb + (size_t)kt * (64 * 16);
            shortx8 kf0 = *(const shortx8*)(p);       // coalesced: lane*32B
            shortx8 kf1 = *(const shortx8*)(p + 8);
            floatx4 acc = {0.f, 0.f, 0.f, 0.f};
            acc = __builtin_amdgcn_mfma_f32_16x16x32_bf16(qf0, kf0, acc, 0, 0, 0);
            acc = __builtin_amdgcn_mfma_f32_16x16x32_bf16(qf1, kf1, acc, 0, 0, 0);
            int n0 = kt << 4;
            int col = n0 + l15;
            int mv = mrow[col];                       // L1-served, 16 ints/wave
            #pragma unroll
            for (int r = 0; r < 4; ++r) {
                // C/D: row(q within 16-tile) = quad*4+r, col(key) = lane&15
                unsigned short h = mv ? f32_to_bf16(acc[r] * 0.125f)
                                      : (unsigned short)0xC61C;  // bf16(-10000)
                sc[(quad * 4 + r) * SCN + col] = h;
            }
        }
    }
    __syncthreads();   // the only barrier

    // ---- Phase 2 (waves 0..3): row softmax -> attn_weight ----
    // ---- Phase 3 (waves 4..7): O = Sc @ V                   ----
    // Independent (reference bug: O uses raw masked scores).
    if (w < 4) {
        float* attnb = out + ATTN_OFF + ((size_t)(bh * S_ + q0)) * S_;
        #pragma unroll
        for (int rr = 0; rr < 4; ++rr) {
            int row = (w << 2) + rr;                 // rows 0..15
            const unsigned short* srow = sc + row * SCN;
            float vv[16];
            #pragma unroll
            for (int c = 0; c < 2; ++c) {
                ushortx8 h = *(const ushortx8*)(srow + (c << 9) + lane * 8);
                #pragma unroll
                for (int j = 0; j < 8; ++j) vv[c * 8 + j] = bf16_to_f32(h[j]);
            }
            float m = vv[0];
            #pragma unroll
            for (int j = 1; j < 16; ++j) m = fmaxf(m, vv[j]);
            #pragma unroll
            for (int off = 32; off; off >>= 1) m = fmaxf(m, __shfl_xor(m, off));
            float s = 0.f;
            #pragma unroll
            for (int j = 0; j < 16; ++j) { vv[j] = __expf(vv[j] - m); s += vv[j]; }
            #pragma unroll
            for (int off = 32; off; off >>= 1) s += __shfl_xor(s, off);
            float inv = 1.0f / s;
            float* arow = attnb + (size_t)row * S_ + lane * 8;
            #pragma unroll
            for (int c = 0; c < 2; ++c) {
                floatx4 o0 = { vv[c*8+0]*inv, vv[c*8+1]*inv, vv[c*8+2]*inv, vv[c*8+3]*inv };
                floatx4 o1 = { vv[c*8+4]*inv, vv[c*8+5]*inv, vv[c*8+6]*inv, vv[c*8+7]*inv };
                *(floatx4*)(arow + (c << 9))     = o0;
                *(floatx4*)(arow + (c << 9) + 4) = o1;
            }
        }
    } else {
        // PV wave: cg = w-4 owns d cols [cg*16, cg*16+16) for the 16 rows.
        int cg = w - 4;
        const unsigned short* vb = VtP + (((size_t)bh * 4 + cg) * 32) * (64 * 8) + lane * 8;
        const unsigned short* sr = sc + l15 * SCN + quad * 8;
        floatx4 oacc = {0.f, 0.f, 0.f, 0.f};
        #pragma unroll 2
        for (int ks = 0; ks < 32; ++ks) {
            shortx8 af = *(const shortx8*)(sr + (ks << 5));        // LDS A-frag
            shortx8 bf = *(const shortx8*)(vb + (ks << 9));        // coalesced 16B/lane
            oacc = __builtin_amdgcn_mfma_f32_16x16x32_bf16(af, bf, oacc, 0, 0, 0);
        }
        float* ob = out + ((size_t)(bh * S_ + q0 + (quad << 2))) * D_
                        + (cg << 4) + l15;
        #pragma unroll
        for (int r = 0; r < 4; ++r) ob[(size_t)r * D_] = oacc[r];
    }
}

extern "C" void kernel_launch(void* const* d_in, const int* in_sizes, int n_in,
                              void* d_out, int out_size, void* d_ws, size_t ws_size,
                              hipStream_t stream) {
    const float* q   = (const float*)d_in[0];
    const float* k   = (const float*)d_in[1];
    const float* v   = (const float*)d_in[2];
    const int* mask  = (const int*)d_in[3];
    float* out = (float*)d_out;
    unsigned short* KbT = (unsigned short*)d_ws;       // 8 MB
    unsigned short* VtP = KbT + NELEM_;                // 8 MB
    pack_kv<<<2048, 256, 0, stream>>>(k, v, KbT, VtP);
    attn_main<<<4096, 512, 0, stream>>>(q, mask, KbT, VtP, out);
}